// Round 18
// baseline (232.142 us; speedup 1.0000x reference)
//
#include <hip/hip_runtime.h>
#include <hip/hip_bf16.h>
#include <cstdint>
#include <cstddef>

#define S_LEN   4096
#define BATCHN  4
#define DMODEL  1024
#define NHEADS  16
#define HDIM    64
#define MROWS   (S_LEN*BATCHN)   // 16384
#define KDIM    1024
#define NTK     (KDIM/32)        // 32 K-steps
#define CLP     136              // padded C-tile pitch (elements)

typedef __bf16 bf16;
typedef bf16 bf16x8 __attribute__((ext_vector_type(8)));
typedef bf16 bf16x4 __attribute__((ext_vector_type(4)));
typedef float f32x4 __attribute__((ext_vector_type(4)));

#define MFMA16(a,b,c) __builtin_amdgcn_mfma_f32_16x16x32_bf16(a,b,c,0,0,0)

__device__ __forceinline__ void gll16(const void* g, void* l) {
  __builtin_amdgcn_global_load_lds((const __attribute__((address_space(1))) unsigned*)g,
                                   (__attribute__((address_space(3))) unsigned*)l,
                                   16, 0, 0);
}

// ---------------- single cast kernel: h,x ([S][B][D]->[B][S][D]) + 4 weights ---------
__global__ __launch_bounds__(256) void cast_all(
    const float* __restrict__ h, const float* __restrict__ x,
    const float* __restrict__ Wq, const float* __restrict__ Wk,
    const float* __restrict__ Wv, const float* __restrict__ Wo,
    bf16* __restrict__ dst) {
  const int nperm = MROWS * KDIM;                 // 16,777,216
  const int ntot  = 2 * nperm + 4 * 1048576;      // 37,748,736
  int stride = gridDim.x * blockDim.x * 4;
  for (int i = (blockIdx.x * blockDim.x + threadIdx.x) * 4; i < ntot; i += stride) {
    if (i < 2 * nperm) {
      const bool isH = (i < nperm);
      const int j = isH ? i : i - nperm;
      int s = j >> 12, b = (j >> 10) & 3, d = j & 1023;
      size_t o = ((size_t)(b * S_LEN + s) << 10) | d;
      float4 f = *(const float4*)((isH ? h : x) + j);
      bf16x4 u; u[0]=(bf16)f.x; u[1]=(bf16)f.y; u[2]=(bf16)f.z; u[3]=(bf16)f.w;
      *(bf16x4*)(dst + (isH ? 0 : nperm) + o) = u;
    } else {
      int j = i - 2 * nperm;
      int r = j >> 20;
      const float* src = (r < 1) ? (Wq + j) : (r < 2) ? (Wk + j - 1048576)
                       : (r < 3) ? (Wv + j - 2097152) : (Wo + j - 3145728);
      float4 f = *(const float4*)src;
      bf16x4 u; u[0]=(bf16)f.x; u[1]=(bf16)f.y; u[2]=(bf16)f.z; u[3]=(bf16)f.w;
      *(bf16x4*)(dst + i) = u;
    }
  }
}

// ---------------- shared GEMM body: 256x128 block, 4 waves (wave tile 128x64) --------
// 3-buffer counted-vmcnt pipeline. Per buffer: A[256][32] 16KB + B[128][32] 8KB = 24KB;
// 3 buffers = 72KB -> 2 blocks/CU. 6 gll16/thread/step (24 wave-chunks of 1KB), vmcnt(6).
// Swizzle both sides: stored chunk c16 of row holds source elems ((c16^((row>>1)&3))*8..).
struct GemmAcc { f32x4 a[8][4]; };

__device__ __forceinline__ void gemm_tile(const bf16* __restrict__ A,
                                          const bf16* __restrict__ Bw,
                                          size_t arow0, size_t brow0,
                                          bf16* sm, GemmAcc& G) {
  const int tid  = threadIdx.x;
  const int wid  = tid >> 6;
  const int lane = tid & 63;
  const int wm = wid >> 1, wn = wid & 1;
  const int fhalf = (lane >> 4) << 4;

  const bf16* sp[6]; int sd[6];
  #pragma unroll
  for (int j = 0; j < 6; ++j) {
    int c = wid * 6 + j;
    int row; const bf16* src; int dstE;
    if (c < 16) { row = c * 16 + (lane >> 2); src = A  + (arow0 + row) * KDIM; dstE = c * 512; }
    else { int cb = c - 16; row = cb * 16 + (lane >> 2); src = Bw + (brow0 + row) * KDIM; dstE = 8192 + cb * 512; }
    int c16 = lane & 3;
    sp[j] = src + ((c16 ^ ((row >> 1) & 3)) * 8);
    sd[j] = dstE;
  }

  #pragma unroll
  for (int j = 0; j < 6; ++j) gll16(sp[j],      sm + sd[j]);
  #pragma unroll
  for (int j = 0; j < 6; ++j) gll16(sp[j] + 32, sm + 12288 + sd[j]);
  asm volatile("s_waitcnt vmcnt(6)" ::: "memory");
  __builtin_amdgcn_s_barrier();
  asm volatile("" ::: "memory");

  int cur = 0;
  for (int t = 0; t < NTK; ++t) {
    const char* As = (const char*)(sm + cur * 12288);
    const char* Bs = As + 16384;

    bf16x8 af[8], bfv[4];
    #pragma unroll
    for (int m = 0; m < 8; ++m) {
      int R = wm*128 + m*16 + (lane & 15);
      af[m] = *(const bf16x8*)(As + R*64 + (fhalf ^ (((R >> 1) & 3) << 4)));
    }
    #pragma unroll
    for (int n = 0; n < 4; ++n) {
      int R = wn*64 + n*16 + (lane & 15);
      bfv[n] = *(const bf16x8*)(Bs + R*64 + (fhalf ^ (((R >> 1) & 3) << 4)));
    }

    if (t + 2 < NTK) {
      int nx2 = cur + 2; if (nx2 >= 3) nx2 -= 3;
      bf16* wb = sm + nx2 * 12288;
      const int ko = (t + 2) * 32;
      #pragma unroll
      for (int j = 0; j < 6; ++j) gll16(sp[j] + ko, wb + sd[j]);
    }

    #pragma unroll
    for (int m = 0; m < 8; ++m)
      #pragma unroll
      for (int n = 0; n < 4; ++n)
        G.a[m][n] = MFMA16(af[m], bfv[n], G.a[m][n]);

    if (t < NTK - 2)       asm volatile("s_waitcnt vmcnt(6)" ::: "memory");
    else if (t == NTK - 2) asm volatile("s_waitcnt vmcnt(0)" ::: "memory");
    if (t < NTK - 1) {
      __builtin_amdgcn_s_barrier();
      asm volatile("" ::: "memory");
    }
    cur = (cur == 2) ? 0 : cur + 1;
  }
}

// ---------------- Q projection + elu + Z + scale: qs = (elu(h@Wq^T+bq)+1)/Z ----------
__global__ __launch_bounds__(256, 2) void q_gemm(
    const bf16* __restrict__ A, const bf16* __restrict__ Bw,
    const float* __restrict__ bq, const float* __restrict__ Ksumg,
    bf16* __restrict__ qs) {
  __shared__ __align__(16) bf16 sm[3 * 12288];   // 72 KB
  const int tid  = threadIdx.x;
  const int wid  = tid >> 6;
  const int lane = tid & 63;
  const int wm = wid >> 1, wn = wid & 1;
  const int bid = blockIdx.x;
  const int xcd = bid & 7, local = bid >> 3;
  const int mtile = xcd * 8 + (local >> 3);      // 0..63, 256 rows each
  const int ntile = local & 7;

  GemmAcc G = {};
  gemm_tile(A, Bw, (size_t)mtile * 256, (size_t)ntile * 128, sm, G);

  const int hgg = (mtile >> 4) * 16 + ntile * 2 + wn;   // global (b,h)
  float ksl[4], bql[4];
  #pragma unroll
  for (int n = 0; n < 4; ++n) {
    ksl[n] = Ksumg[hgg*64 + n*16 + (lane & 15)];
    bql[n] = bq[ntile*128 + wn*64 + n*16 + (lane & 15)];
  }

  #pragma unroll
  for (int m = 0; m < 8; ++m) {
    #pragma unroll
    for (int i = 0; i < 4; ++i) {
      int row = mtile*256 + wm*128 + m*16 + ((lane >> 4) << 2) + i;
      float v[4], zp = 0.f;
      #pragma unroll
      for (int n = 0; n < 4; ++n) {
        float t = G.a[m][n][i] + bql[n];
        t = (t > 0.f) ? t + 1.f : __expf(t);     // elu+1
        v[n] = t;
        zp += t * ksl[n];
      }
      zp += __shfl_xor(zp, 1);
      zp += __shfl_xor(zp, 2);
      zp += __shfl_xor(zp, 4);
      zp += __shfl_xor(zp, 8);
      float rz = 1.f / (zp + 1e-6f);
      #pragma unroll
      for (int n = 0; n < 4; ++n) {
        int col = ntile*128 + wn*64 + n*16 + (lane & 15);
        qs[(size_t)row*DMODEL + col] = (bf16)(v[n] * rz);
      }
    }
  }
}

// ---------------- output GEMM: d_out[s*4+b] = qs[b*4096+s] @ B2_b^T + bo -------------
__global__ __launch_bounds__(256, 2) void out_gemm(const bf16* __restrict__ qsA,
                                                   const bf16* __restrict__ B2,
                                                   const float* __restrict__ bo,
                                                   float* __restrict__ Cout) {
  __shared__ __align__(16) bf16 sm[3 * 12288];   // 72 KB
  const int tid  = threadIdx.x;
  const int wid  = tid >> 6;
  const int lane = tid & 63;
  const int wm = wid >> 1, wn = wid & 1;
  const int bid = blockIdx.x;
  const int xcd = bid & 7, local = bid >> 3;
  const int mtile = xcd * 8 + (local >> 3);
  const int ntile = local & 7;
  const bf16* Bw = B2 + (size_t)(mtile >> 4) * 1048576;   // per-batch B2

  GemmAcc G = {};
  gemm_tile(qsA, Bw, (size_t)mtile * 256, (size_t)ntile * 128, sm, G);

  #pragma unroll
  for (int m = 0; m < 8; ++m) {
    #pragma unroll
    for (int n = 0; n < 4; ++n) {
      int col = ntile*128 + wn*64 + n*16 + (lane & 15);
      float bias = bo[col];
      #pragma unroll
      for (int i = 0; i < 4; ++i) {
        int g = mtile*256 + wm*128 + m*16 + ((lane >> 4) << 2) + i;   // b*4096 + s
        int orow = ((g & 4095) << 2) | (g >> 12);                     // s*4 + b
        Cout[(size_t)orow*DMODEL + col] = G.a[m][n][i] + bias;
      }
    }
  }
}

// ---------------- fused KV projection + KV/Ksum reduction: 256 threads, 128x64 tile --
// A-tile rows 0..127 = Wkv K rows mB*128.., rows 128..255 = Wkv V rows 1024+mB*128..
// (wave-uniform per staging chunk: c 0..7 -> K, 8..15 -> V). Same pipeline as gemm_tile.
// Epilogue: CL [256][CLP] bf16 -> per-head KV (4 waves: hl=wid>>1, ww=wid&1) + Ksum.
__global__ __launch_bounds__(256, 2) void kvproj(
    const bf16* __restrict__ Wkv, const bf16* __restrict__ xb,
    const float* __restrict__ bk, const float* __restrict__ bv,
    float* __restrict__ kvb, float* __restrict__ ksb) {
  __shared__ __align__(16) bf16 sm[3 * 12288];   // 72 KB
  const int tid  = threadIdx.x;
  const int wid  = tid >> 6;
  const int lane = tid & 63;
  const int wm = wid >> 1, wn = wid & 1;
  const int bid = blockIdx.x;
  const int xcd = bid & 7, local = bid >> 3;
  const int ntile = xcd * 16 + (local >> 3);     // xb s-block (128 cols)
  const int mB = local & 7;                      // Wkv panel (128 K + 128 V rows)
  const int fhalf = (lane >> 4) << 4;

  const bf16* KA = Wkv + (size_t)(mB * 128) * KDIM;
  const bf16* VA = Wkv + (size_t)(1024 + mB * 128) * KDIM;
  const bf16* BB = xb + (size_t)(ntile * 128) * KDIM;

  // staging: 6 wave-uniform 1KB chunks per wave; A chunks 0..15 (K:0..7, V:8..15), B 16..23
  const bf16* sp[6]; int sd[6];
  #pragma unroll
  for (int j = 0; j < 6; ++j) {
    int c = wid * 6 + j;
    int row; const bf16* src; int dstE;
    if (c < 16) {
      row = c * 16 + (lane >> 2);
      src = (row < 128) ? (KA + (size_t)row * KDIM) : (VA + (size_t)(row - 128) * KDIM);
      dstE = c * 512;
    } else {
      int cb = c - 16; row = cb * 16 + (lane >> 2);
      src = BB + (size_t)row * KDIM; dstE = 8192 + cb * 512;
    }
    int c16 = lane & 3;
    sp[j] = src + ((c16 ^ ((row >> 1) & 3)) * 8);
    sd[j] = dstE;
  }

  #pragma unroll
  for (int j = 0; j < 6; ++j) gll16(sp[j],      sm + sd[j]);
  #pragma unroll
  for (int j = 0; j < 6; ++j) gll16(sp[j] + 32, sm + 12288 + sd[j]);
  asm volatile("s_waitcnt vmcnt(6)" ::: "memory");
  __builtin_amdgcn_s_barrier();
  asm volatile("" ::: "memory");

  f32x4 acc[8][4] = {};
  int cur = 0;
  for (int t = 0; t < NTK; ++t) {
    const char* As = (const char*)(sm + cur * 12288);
    const char* Bs = As + 16384;

    bf16x8 af[8], bfv[4];
    #pragma unroll
    for (int m = 0; m < 8; ++m) {
      int R = wm*128 + m*16 + (lane & 15);
      af[m] = *(const bf16x8*)(As + R*64 + (fhalf ^ (((R >> 1) & 3) << 4)));
    }
    #pragma unroll
    for (int n = 0; n < 4; ++n) {
      int R = wn*64 + n*16 + (lane & 15);
      bfv[n] = *(const bf16x8*)(Bs + R*64 + (fhalf ^ (((R >> 1) & 3) << 4)));
    }

    if (t + 2 < NTK) {
      int nx2 = cur + 2; if (nx2 >= 3) nx2 -= 3;
      bf16* wb = sm + nx2 * 12288;
      const int ko = (t + 2) * 32;
      #pragma unroll
      for (int j = 0; j < 6; ++j) gll16(sp[j] + ko, wb + sd[j]);
    }

    #pragma unroll
    for (int m = 0; m < 8; ++m)
      #pragma unroll
      for (int n = 0; n < 4; ++n)
        acc[m][n] = MFMA16(af[m], bfv[n], acc[m][n]);

    if (t < NTK - 2)       asm volatile("s_waitcnt vmcnt(6)" ::: "memory");
    else if (t == NTK - 2) asm volatile("s_waitcnt vmcnt(0)" ::: "memory");
    if (t < NTK - 1) {
      __builtin_amdgcn_s_barrier();
      asm volatile("" ::: "memory");
    }
    cur = (cur == 2) ? 0 : cur + 1;
  }
  __syncthreads();   // all LDS reads done before C-store reuses sm

  // ---- C tile (bias + elu on K rows) -> LDS [256][CLP] bf16 ----
  bf16* CL = sm;
  #pragma unroll
  for (int m = 0; m < 8; ++m) {
    #pragma unroll
    for (int i = 0; i < 4; ++i) {
      int ra = wm*128 + m*16 + ((lane >> 4) << 2) + i;
      float bias = (ra < 128) ? bk[mB*128 + ra] : bv[mB*128 + ra - 128];
      #pragma unroll
      for (int n = 0; n < 4; ++n) {
        int cb = wn*64 + n*16 + (lane & 15);
        float v = acc[m][n][i] + bias;
        if (ra < 128) v = (v > 0.f) ? v + 1.f : __expf(v);   // elu(k)+1
        CL[ra*CLP + cb] = (bf16)v;
      }
    }
  }
  __syncthreads();

  // ---- KV_h = Kp_h @ Vp_h^T over this 128-s block, K=128 (4 waves) ----
  const int hl = wid >> 1;          // head-local 0..1
  const int ww = wid & 1;           // 32-row d-slice within head
  const int bh = (ntile >> 5) * 16 + 2*mB + hl;
  f32x4 acc2[2][4] = {};
  #pragma unroll
  for (int ks = 0; ks < 4; ++ks) {
    #pragma unroll
    for (int m2 = 0; m2 < 2; ++m2) {
      bf16x8 akv = *(const bf16x8*)(CL + (hl*64 + ww*32 + m2*16 + (lane & 15))*CLP + ks*32 + ((lane >> 4) << 3));
      #pragma unroll
      for (int nn = 0; nn < 4; ++nn) {
        bf16x8 bkv = *(const bf16x8*)(CL + (128 + hl*64 + nn*16 + (lane & 15))*CLP + ks*32 + ((lane >> 4) << 3));
        acc2[m2][nn] = MFMA16(akv, bkv, acc2[m2][nn]);
      }
    }
  }
  float* KVh = kvb + (size_t)bh * 4096;
  #pragma unroll
  for (int m2 = 0; m2 < 2; ++m2)
    #pragma unroll
    for (int nn = 0; nn < 4; ++nn)
      #pragma unroll
      for (int i = 0; i < 4; ++i) {
        int dd = ww*32 + m2*16 + ((lane >> 4) << 2) + i;
        int vv = nn*16 + (lane & 15);
        atomicAdd(&KVh[dd*64 + vv], acc2[m2][nn][i]);
      }

  // ---- Ksum over K rows (256 threads: 128 rows x 2 parts) ----
  {
    int rid = tid >> 1, part = tid & 1;
    float s = 0.f;
    #pragma unroll
    for (int j = 0; j < 64; ++j) s += (float)CL[rid*CLP + part*64 + j];
    s += __shfl_xor(s, 1);
    if (part == 0) {
      int hh = rid >> 6, d = rid & 63;
      atomicAdd(&ksb[((ntile >> 5) * 16 + 2*mB + hh)*64 + d], s);
    }
  }
}

// ---------------- B2_b[o][h*64+d] = sum_v KV_{b,h}[d][v] * Wo[o][h*64+v] -------------
__global__ __launch_bounds__(256) void w2_gemm(const bf16* __restrict__ wob,
                                               const float* __restrict__ kvb,
                                               bf16* __restrict__ B2) {
  const int mtile = blockIdx.x, bh = blockIdx.y;
  const int b = bh >> 4, hh = bh & 15;
  const int tid = threadIdx.x;
  const int wid = tid >> 6, lane = tid & 63;
  __shared__ __align__(16) bf16 Wos[128*64];
  __shared__ __align__(16) bf16 KVs[64*64];     // [d][v]

  #pragma unroll
  for (int it = 0; it < 4; ++it) {
    int idx = it*256 + tid;
    int row = idx >> 3, c = (idx & 7) << 3;
    *(bf16x8*)(Wos + row*64 + c) =
      *(const bf16x8*)(wob + (size_t)(mtile*128 + row)*DMODEL + hh*64 + c);
  }
  const float* KVh = kvb + (size_t)bh * 4096;
  #pragma unroll
  for (int it = 0; it < 16; ++it) {
    int idx = it*256 + tid;
    KVs[idx] = (bf16)KVh[idx];
  }
  __syncthreads();

  f32x4 acc[2][4] = {};
  #pragma unroll
  for (int ks = 0; ks < 2; ++ks) {
    bf16x8 af[2], bv[4];
    #pragma unroll
    for (int m = 0; m < 2; ++m)
      af[m] = *(const bf16x8*)(Wos + (wid*32 + m*16 + (lane & 15))*64 + ks*32 + ((lane>>4)<<3));
    #pragma unroll
    for (int n = 0; n < 4; ++n)
      bv[n] = *(const bf16x8*)(KVs + (n*16 + (lane & 15))*64 + ks*32 + ((lane>>4)<<3));
    #pragma unroll
    for (int m = 0; m < 2; ++m)
      #pragma unroll
      for (int n = 0; n < 4; ++n)
        acc[m][n] = MFMA16(af[m], bv[n], acc[m][n]);
  }

  bf16* B2b = B2 + (size_t)b * 1048576;
  #pragma unroll
  for (int m = 0; m < 2; ++m)
    #pragma unroll
    for (int n = 0; n < 4; ++n)
      #pragma unroll
      for (int i = 0; i < 4; ++i) {
        int orow = mtile*128 + wid*32 + m*16 + ((lane >> 4) << 2) + i;
        int dd   = n*16 + (lane & 15);
        B2b[(size_t)orow*DMODEL + hh*64 + dd] = (bf16)acc[m][n][i];
      }
}

// ---------------- launch ----------------
extern "C" void kernel_launch(void* const* d_in, const int* in_sizes, int n_in,
                              void* d_out, int out_size, void* d_ws, size_t ws_size,
                              hipStream_t stream) {
  const float* h  = (const float*)d_in[0];
  const float* x  = (const float*)d_in[1];
  const float* Wq = (const float*)d_in[2];
  const float* bq = (const float*)d_in[3];
  const float* Wk = (const float*)d_in[4];
  const float* bk = (const float*)d_in[5];
  const float* Wv = (const float*)d_in[6];
  const float* bv = (const float*)d_in[7];
  const float* Wo = (const float*)d_in[8];
  const float* bo = (const float*)d_in[9];

  char* ws = (char*)d_ws;
  bf16*  hb   = (bf16*)(ws);                    // 33,554,432 B  [B][S][D]
  bf16*  xb   = (bf16*)(ws + 33554432);         // 33,554,432 B  [B][S][D]
  bf16*  wcat = (bf16*)(ws + 67108864);         //  6,291,456 B  Wq|Wk|Wv [3072][1024]
  bf16*  wob  = (bf16*)(ws + 73400320);         //  2,097,152 B  [1024][1024]
  bf16*  qs   = (bf16*)(ws + 75497472);         // 33,554,432 B  [16384 b*s][1024]
  float* kvb  = (float*)(ws + 109051904);       //  1,048,576 B  [64][64][64]
  float* ksb  = (float*)(ws + 110100480);       //     16,384 B  [64][64]
  bf16*  B2   = (bf16*)(ws + 110116864);        //  8,388,608 B  [4][1024][1024]

  cast_all<<<dim3(4096), 256, 0, stream>>>(h, x, Wq, Wk, Wv, Wo, hb);

  hipMemsetAsync(kvb, 0, 1048576 + 16384, stream);

  kvproj<<<dim3(1024), 256, 0, stream>>>(wcat + 1048576, xb, bk, bv, kvb, ksb);
  w2_gemm<<<dim3(8, 64), 256, 0, stream>>>(wob, kvb, B2);
  q_gemm<<<dim3(512), 256, 0, stream>>>(hb, wcat, bq, ksb, qs);
  out_gemm<<<dim3(512), 256, 0, stream>>>(qs, B2, bo, (float*)d_out);
}

// Round 19
// 220.561 us; speedup vs baseline: 1.0525x; 1.0525x over previous
//
#include <hip/hip_runtime.h>
#include <hip/hip_bf16.h>
#include <cstdint>
#include <cstddef>

#define S_LEN   4096
#define BATCHN  4
#define DMODEL  1024
#define NHEADS  16
#define HDIM    64
#define MROWS   (S_LEN*BATCHN)   // 16384
#define KDIM    1024
#define NTK     (KDIM/32)        // 32 K-steps
#define CLP     136              // padded C-tile pitch (elements)

typedef __bf16 bf16;
typedef bf16 bf16x8 __attribute__((ext_vector_type(8)));
typedef bf16 bf16x4 __attribute__((ext_vector_type(4)));
typedef float f32x4 __attribute__((ext_vector_type(4)));

#define MFMA16(a,b,c) __builtin_amdgcn_mfma_f32_16x16x32_bf16(a,b,c,0,0,0)

__device__ __forceinline__ void gll16(const void* g, void* l) {
  __builtin_amdgcn_global_load_lds((const __attribute__((address_space(1))) unsigned*)g,
                                   (__attribute__((address_space(3))) unsigned*)l,
                                   16, 0, 0);
}

// ---------------- single cast kernel: h,x ([S][B][D]->[B][S][D]) + 4 weights ---------
__global__ __launch_bounds__(256) void cast_all(
    const float* __restrict__ h, const float* __restrict__ x,
    const float* __restrict__ Wq, const float* __restrict__ Wk,
    const float* __restrict__ Wv, const float* __restrict__ Wo,
    bf16* __restrict__ dst) {
  const int nperm = MROWS * KDIM;                 // 16,777,216
  const int ntot  = 2 * nperm + 4 * 1048576;      // 37,748,736
  int stride = gridDim.x * blockDim.x * 4;
  for (int i = (blockIdx.x * blockDim.x + threadIdx.x) * 4; i < ntot; i += stride) {
    if (i < 2 * nperm) {
      const bool isH = (i < nperm);
      const int j = isH ? i : i - nperm;
      int s = j >> 12, b = (j >> 10) & 3, d = j & 1023;
      size_t o = ((size_t)(b * S_LEN + s) << 10) | d;
      float4 f = *(const float4*)((isH ? h : x) + j);
      bf16x4 u; u[0]=(bf16)f.x; u[1]=(bf16)f.y; u[2]=(bf16)f.z; u[3]=(bf16)f.w;
      *(bf16x4*)(dst + (isH ? 0 : nperm) + o) = u;
    } else {
      int j = i - 2 * nperm;
      int r = j >> 20;
      const float* src = (r < 1) ? (Wq + j) : (r < 2) ? (Wk + j - 1048576)
                       : (r < 3) ? (Wv + j - 2097152) : (Wo + j - 3145728);
      float4 f = *(const float4*)src;
      bf16x4 u; u[0]=(bf16)f.x; u[1]=(bf16)f.y; u[2]=(bf16)f.z; u[3]=(bf16)f.w;
      *(bf16x4*)(dst + i) = u;
    }
  }
}

// ---------------- shared GEMM body: 256x128 block, 4 waves (wave tile 128x64) --------
// 3-buffer counted-vmcnt pipeline. Per buffer: A[256][32] 16KB + B[128][32] 8KB = 24KB;
// 3 buffers = 72KB -> 2 blocks/CU. 6 gll16/thread/step (24 wave-chunks of 1KB), vmcnt(6).
struct GemmAcc { f32x4 a[8][4]; };

__device__ __forceinline__ void gemm_tile(const bf16* __restrict__ A,
                                          const bf16* __restrict__ Bw,
                                          size_t arow0, size_t brow0,
                                          bf16* sm, GemmAcc& G) {
  const int tid  = threadIdx.x;
  const int wid  = tid >> 6;
  const int lane = tid & 63;
  const int wm = wid >> 1, wn = wid & 1;
  const int fhalf = (lane >> 4) << 4;

  const bf16* sp[6]; int sd[6];
  #pragma unroll
  for (int j = 0; j < 6; ++j) {
    int c = wid * 6 + j;
    int row; const bf16* src; int dstE;
    if (c < 16) { row = c * 16 + (lane >> 2); src = A  + (arow0 + row) * KDIM; dstE = c * 512; }
    else { int cb = c - 16; row = cb * 16 + (lane >> 2); src = Bw + (brow0 + row) * KDIM; dstE = 8192 + cb * 512; }
    int c16 = lane & 3;
    sp[j] = src + ((c16 ^ ((row >> 1) & 3)) * 8);
    sd[j] = dstE;
  }

  #pragma unroll
  for (int j = 0; j < 6; ++j) gll16(sp[j],      sm + sd[j]);
  #pragma unroll
  for (int j = 0; j < 6; ++j) gll16(sp[j] + 32, sm + 12288 + sd[j]);
  asm volatile("s_waitcnt vmcnt(6)" ::: "memory");
  __builtin_amdgcn_s_barrier();
  asm volatile("" ::: "memory");

  int cur = 0;
  for (int t = 0; t < NTK; ++t) {
    const char* As = (const char*)(sm + cur * 12288);
    const char* Bs = As + 16384;

    bf16x8 af[8], bfv[4];
    #pragma unroll
    for (int m = 0; m < 8; ++m) {
      int R = wm*128 + m*16 + (lane & 15);
      af[m] = *(const bf16x8*)(As + R*64 + (fhalf ^ (((R >> 1) & 3) << 4)));
    }
    #pragma unroll
    for (int n = 0; n < 4; ++n) {
      int R = wn*64 + n*16 + (lane & 15);
      bfv[n] = *(const bf16x8*)(Bs + R*64 + (fhalf ^ (((R >> 1) & 3) << 4)));
    }

    if (t + 2 < NTK) {
      int nx2 = cur + 2; if (nx2 >= 3) nx2 -= 3;
      bf16* wb = sm + nx2 * 12288;
      const int ko = (t + 2) * 32;
      #pragma unroll
      for (int j = 0; j < 6; ++j) gll16(sp[j] + ko, wb + sd[j]);
    }

    #pragma unroll
    for (int m = 0; m < 8; ++m)
      #pragma unroll
      for (int n = 0; n < 4; ++n)
        G.a[m][n] = MFMA16(af[m], bfv[n], G.a[m][n]);

    if (t < NTK - 2)       asm volatile("s_waitcnt vmcnt(6)" ::: "memory");
    else if (t == NTK - 2) asm volatile("s_waitcnt vmcnt(0)" ::: "memory");
    if (t < NTK - 1) {
      __builtin_amdgcn_s_barrier();
      asm volatile("" ::: "memory");
    }
    cur = (cur == 2) ? 0 : cur + 1;
  }
}

// ---------------- Q projection + elu + Z + scale: qs = (elu(h@Wq^T+bq)+1)/Z ----------
__global__ __launch_bounds__(256, 2) void q_gemm(
    const bf16* __restrict__ A, const bf16* __restrict__ Bw,
    const float* __restrict__ bq, const float* __restrict__ Ksumg,
    bf16* __restrict__ qs) {
  __shared__ __align__(16) bf16 sm[3 * 12288];   // 72 KB
  const int tid  = threadIdx.x;
  const int wid  = tid >> 6;
  const int lane = tid & 63;
  const int wm = wid >> 1, wn = wid & 1;
  const int bid = blockIdx.x;
  const int xcd = bid & 7, local = bid >> 3;
  const int mtile = xcd * 8 + (local >> 3);      // 0..63, 256 rows each
  const int ntile = local & 7;

  GemmAcc G = {};
  gemm_tile(A, Bw, (size_t)mtile * 256, (size_t)ntile * 128, sm, G);

  const int hgg = (mtile >> 4) * 16 + ntile * 2 + wn;   // global (b,h)
  float ksl[4], bql[4];
  #pragma unroll
  for (int n = 0; n < 4; ++n) {
    ksl[n] = Ksumg[hgg*64 + n*16 + (lane & 15)];
    bql[n] = bq[ntile*128 + wn*64 + n*16 + (lane & 15)];
  }

  #pragma unroll
  for (int m = 0; m < 8; ++m) {
    #pragma unroll
    for (int i = 0; i < 4; ++i) {
      int row = mtile*256 + wm*128 + m*16 + ((lane >> 4) << 2) + i;
      float v[4], zp = 0.f;
      #pragma unroll
      for (int n = 0; n < 4; ++n) {
        float t = G.a[m][n][i] + bql[n];
        t = (t > 0.f) ? t + 1.f : __expf(t);     // elu+1
        v[n] = t;
        zp += t * ksl[n];
      }
      zp += __shfl_xor(zp, 1);
      zp += __shfl_xor(zp, 2);
      zp += __shfl_xor(zp, 4);
      zp += __shfl_xor(zp, 8);
      float rz = 1.f / (zp + 1e-6f);
      #pragma unroll
      for (int n = 0; n < 4; ++n) {
        int col = ntile*128 + wn*64 + n*16 + (lane & 15);
        qs[(size_t)row*DMODEL + col] = (bf16)(v[n] * rz);
      }
    }
  }
}

// ---------------- output GEMM: d_out[s*4+b] = qs[b*4096+s] @ B2_b^T + bo -------------
__global__ __launch_bounds__(256, 2) void out_gemm(const bf16* __restrict__ qsA,
                                                   const bf16* __restrict__ B2,
                                                   const float* __restrict__ bo,
                                                   float* __restrict__ Cout) {
  __shared__ __align__(16) bf16 sm[3 * 12288];   // 72 KB
  const int tid  = threadIdx.x;
  const int wid  = tid >> 6;
  const int lane = tid & 63;
  const int wm = wid >> 1, wn = wid & 1;
  const int bid = blockIdx.x;
  const int xcd = bid & 7, local = bid >> 3;
  const int mtile = xcd * 8 + (local >> 3);
  const int ntile = local & 7;
  const bf16* Bw = B2 + (size_t)(mtile >> 4) * 1048576;   // per-batch B2

  GemmAcc G = {};
  gemm_tile(qsA, Bw, (size_t)mtile * 256, (size_t)ntile * 128, sm, G);

  #pragma unroll
  for (int m = 0; m < 8; ++m) {
    #pragma unroll
    for (int n = 0; n < 4; ++n) {
      int col = ntile*128 + wn*64 + n*16 + (lane & 15);
      float bias = bo[col];
      #pragma unroll
      for (int i = 0; i < 4; ++i) {
        int g = mtile*256 + wm*128 + m*16 + ((lane >> 4) << 2) + i;   // b*4096 + s
        int orow = ((g & 4095) << 2) | (g >> 12);                     // s*4 + b
        Cout[(size_t)orow*DMODEL + col] = G.a[m][n][i] + bias;
      }
    }
  }
}

// ---------------- fused KV projection + KV/Ksum reduction (512-thread, proven) -------
__global__ __launch_bounds__(512, 4) void kvproj(
    const bf16* __restrict__ Wkv, const bf16* __restrict__ xb,
    const float* __restrict__ bk, const float* __restrict__ bv,
    float* __restrict__ kvb, float* __restrict__ ksb) {
  __shared__ __align__(16) bf16 sm[3 * 12288];   // 72 KB
  const int tid  = threadIdx.x;
  const int wid  = tid >> 6;
  const int lane = tid & 63;
  const int wm = wid >> 1, wn = wid & 1;
  const int bid = blockIdx.x;
  const int xcd = bid & 7, local = bid >> 3;
  const int ntile = xcd * 16 + (local >> 3);
  const int m = local & 7;
  const int lr = lane >> 2;
  const int lc = lane & 3;
  const int ssrc = (((lc << 4) ^ (((lr >> 1) & 3) << 4)) >> 1);
  const int fhalf = (lane >> 4) << 4;

  const bf16* KA = Wkv + (size_t)(m * 128) * KDIM;
  const bf16* VA = Wkv + (size_t)(1024 + m * 128) * KDIM;
  const bf16* BB = xb + (size_t)(ntile * 128) * KDIM;

  const bf16* ap[2]; const bf16* bp; int sda[2], sdb;
  #pragma unroll
  for (int i = 0; i < 2; ++i) {
    int seg = (wid << 1) | i;
    const bf16* base = (seg < 8) ? KA : VA;
    ap[i] = base + (size_t)((seg & 7) * 16 + lr) * KDIM + ssrc;
    sda[i] = seg * 512;
  }
  bp = BB + (size_t)(wid * 16 + lr) * KDIM + ssrc;
  sdb = 8192 + wid * 512;

  #pragma unroll
  for (int i = 0; i < 2; ++i) gll16(ap[i], sm + sda[i]);
  gll16(bp, sm + sdb);
  #pragma unroll
  for (int i = 0; i < 2; ++i) gll16(ap[i] + 32, sm + 12288 + sda[i]);
  gll16(bp + 32, sm + 12288 + sdb);
  asm volatile("s_waitcnt vmcnt(3)" ::: "memory");
  __builtin_amdgcn_s_barrier();
  asm volatile("" ::: "memory");

  f32x4 acc[4][4] = {};
  int cur = 0;
  for (int t = 0; t < NTK; ++t) {
    const bf16* As = sm + cur * 12288;
    const bf16* Bs = As + 8192;

    bf16x8 af[4], bfv[4];
    #pragma unroll
    for (int mm = 0; mm < 4; ++mm) {
      int R = wm*64 + mm*16 + (lane & 15);
      af[mm] = *(const bf16x8*)((const char*)As + R*64 + (fhalf ^ (((R >> 1) & 3) << 4)));
    }
    #pragma unroll
    for (int nn = 0; nn < 4; ++nn) {
      int R = wn*64 + nn*16 + (lane & 15);
      bfv[nn] = *(const bf16x8*)((const char*)Bs + R*64 + (fhalf ^ (((R >> 1) & 3) << 4)));
    }

    if (t + 2 < NTK) {
      int nx2 = cur + 2; if (nx2 >= 3) nx2 -= 3;
      bf16* wb = sm + nx2 * 12288;
      const int ko = (t + 2) * 32;
      #pragma unroll
      for (int i = 0; i < 2; ++i) gll16(ap[i] + ko, wb + sda[i]);
      gll16(bp + ko, wb + sdb);
    }

    #pragma unroll
    for (int mm = 0; mm < 4; ++mm)
      #pragma unroll
      for (int nn = 0; nn < 4; ++nn)
        acc[mm][nn] = MFMA16(af[mm], bfv[nn], acc[mm][nn]);

    if (t < NTK - 2)       asm volatile("s_waitcnt vmcnt(3)" ::: "memory");
    else if (t == NTK - 2) asm volatile("s_waitcnt vmcnt(0)" ::: "memory");
    if (t < NTK - 1) {
      __builtin_amdgcn_s_barrier();
      asm volatile("" ::: "memory");
    }
    cur = (cur == 2) ? 0 : cur + 1;
  }
  __syncthreads();

  bf16* CL = sm;
  #pragma unroll
  for (int mm = 0; mm < 4; ++mm) {
    #pragma unroll
    for (int i = 0; i < 4; ++i) {
      int ra = wm*64 + mm*16 + ((lane >> 4) << 2) + i;
      float bias = (ra < 128) ? bk[m*128 + ra] : bv[m*128 + ra - 128];
      #pragma unroll
      for (int nn = 0; nn < 4; ++nn) {
        int cb = wn*64 + nn*16 + (lane & 15);
        float v = acc[mm][nn][i] + bias;
        if (ra < 128) v = (v > 0.f) ? v + 1.f : __expf(v);   // elu(k)+1
        CL[ra*CLP + cb] = (bf16)v;
      }
    }
  }
  __syncthreads();

  const int hl = wid >> 2;
  const int ww = wid & 3;
  const int bh = (ntile >> 5) * 16 + 2*m + hl;
  f32x4 acc2[4] = {};
  #pragma unroll
  for (int ks = 0; ks < 4; ++ks) {
    bf16x8 akv = *(const bf16x8*)(CL + (hl*64 + ww*16 + (lane & 15))*CLP + ks*32 + ((lane >> 4) << 3));
    #pragma unroll
    for (int nn = 0; nn < 4; ++nn) {
      bf16x8 bkv = *(const bf16x8*)(CL + (128 + hl*64 + nn*16 + (lane & 15))*CLP + ks*32 + ((lane >> 4) << 3));
      acc2[nn] = MFMA16(akv, bkv, acc2[nn]);
    }
  }
  float* KVh = kvb + (size_t)bh * 4096;
  #pragma unroll
  for (int nn = 0; nn < 4; ++nn)
    #pragma unroll
    for (int i = 0; i < 4; ++i) {
      int dd = ww*16 + ((lane >> 4) << 2) + i;
      int vv = nn*16 + (lane & 15);
      atomicAdd(&KVh[dd*64 + vv], acc2[nn][i]);
    }

  {
    int rid = tid >> 2, part = tid & 3;
    float s = 0.f;
    #pragma unroll
    for (int j = 0; j < 32; ++j) s += (float)CL[rid*CLP + part*32 + j];
    s += __shfl_xor(s, 1);
    s += __shfl_xor(s, 2);
    if (part == 0) {
      int hh = rid >> 6, d = rid & 63;
      atomicAdd(&ksb[((ntile >> 5) * 16 + 2*m + hh)*64 + d], s);
    }
  }
}

// ---------------- B2_b[o][h*64+d] = sum_v KV_{b,h}[d][v] * Wo[o][h*64+v] -------------
__global__ __launch_bounds__(256) void w2_gemm(const bf16* __restrict__ wob,
                                               const float* __restrict__ kvb,
                                               bf16* __restrict__ B2) {
  const int mtile = blockIdx.x, bh = blockIdx.y;
  const int b = bh >> 4, hh = bh & 15;
  const int tid = threadIdx.x;
  const int wid = tid >> 6, lane = tid & 63;
  __shared__ __align__(16) bf16 Wos[128*64];
  __shared__ __align__(16) bf16 KVs[64*64];     // [d][v]

  #pragma unroll
  for (int it = 0; it < 4; ++it) {
    int idx = it*256 + tid;
    int row = idx >> 3, c = (idx & 7) << 3;
    *(bf16x8*)(Wos + row*64 + c) =
      *(const bf16x8*)(wob + (size_t)(mtile*128 + row)*DMODEL + hh*64 + c);
  }
  const float* KVh = kvb + (size_t)bh * 4096;
  #pragma unroll
  for (int it = 0; it < 16; ++it) {
    int idx = it*256 + tid;
    KVs[idx] = (bf16)KVh[idx];
  }
  __syncthreads();

  f32x4 acc[2][4] = {};
  #pragma unroll
  for (int ks = 0; ks < 2; ++ks) {
    bf16x8 af[2], bv[4];
    #pragma unroll
    for (int m = 0; m < 2; ++m)
      af[m] = *(const bf16x8*)(Wos + (wid*32 + m*16 + (lane & 15))*64 + ks*32 + ((lane>>4)<<3));
    #pragma unroll
    for (int n = 0; n < 4; ++n)
      bv[n] = *(const bf16x8*)(KVs + (n*16 + (lane & 15))*64 + ks*32 + ((lane>>4)<<3));
    #pragma unroll
    for (int m = 0; m < 2; ++m)
      #pragma unroll
      for (int n = 0; n < 4; ++n)
        acc[m][n] = MFMA16(af[m], bv[n], acc[m][n]);
  }

  bf16* B2b = B2 + (size_t)b * 1048576;
  #pragma unroll
  for (int m = 0; m < 2; ++m)
    #pragma unroll
    for (int n = 0; n < 4; ++n)
      #pragma unroll
      for (int i = 0; i < 4; ++i) {
        int orow = mtile*128 + wid*32 + m*16 + ((lane >> 4) << 2) + i;
        int dd   = n*16 + (lane & 15);
        B2b[(size_t)orow*DMODEL + hh*64 + dd] = (bf16)acc[m][n][i];
      }
}

// ---------------- launch ----------------
extern "C" void kernel_launch(void* const* d_in, const int* in_sizes, int n_in,
                              void* d_out, int out_size, void* d_ws, size_t ws_size,
                              hipStream_t stream) {
  const float* h  = (const float*)d_in[0];
  const float* x  = (const float*)d_in[1];
  const float* Wq = (const float*)d_in[2];
  const float* bq = (const float*)d_in[3];
  const float* Wk = (const float*)d_in[4];
  const float* bk = (const float*)d_in[5];
  const float* Wv = (const float*)d_in[6];
  const float* bv = (const float*)d_in[7];
  const float* Wo = (const float*)d_in[8];
  const float* bo = (const float*)d_in[9];

  char* ws = (char*)d_ws;
  bf16*  hb   = (bf16*)(ws);                    // 33,554,432 B  [B][S][D]
  bf16*  xb   = (bf16*)(ws + 33554432);         // 33,554,432 B  [B][S][D]
  bf16*  wcat = (bf16*)(ws + 67108864);         //  6,291,456 B  Wq|Wk|Wv [3072][1024]
  bf16*  wob  = (bf16*)(ws + 73400320);         //  2,097,152 B  [1024][1024]
  bf16*  qs   = (bf16*)(ws + 75497472);         // 33,554,432 B  [16384 b*s][1024]
  float* kvb  = (float*)(ws + 109051904);       //  1,048,576 B  [64][64][64]
  float* ksb  = (float*)(ws + 110100480);       //     16,384 B  [64][64]
  bf16*  B2   = (bf16*)(ws + 110116864);        //  8,388,608 B  [4][1024][1024]

  cast_all<<<dim3(4096), 256, 0, stream>>>(h, x, Wq, Wk, Wv, Wo, hb);

  hipMemsetAsync(kvb, 0, 1048576 + 16384, stream);

  kvproj<<<dim3(1024), 512, 0, stream>>>(wcat + 1048576, xb, bk, bv, kvb, ksb);
  w2_gemm<<<dim3(8, 64), 256, 0, stream>>>(wob, kvb, B2);
  q_gemm<<<dim3(512), 256, 0, stream>>>(hb, wcat, bq, ksb, qs);
  out_gemm<<<dim3(512), 256, 0, stream>>>(qs, B2, bo, (float*)d_out);
}